// Round 3
// baseline (1028.134 us; speedup 1.0000x reference)
//
#include <hip/hip_runtime.h>

#define DEG 16
#define MAX_ITERS 32
#define BLK_F 1024   // fused-path block size (fewer blocks -> cheaper barrier)

// ===========================================================================
// Lightweight grid barrier: generation counter + arrival count.
// One atomic arrival per BLOCK (196 arrivals vs CG's per-block impl on 1563
// blocks in R2). Spin is a relaxed agent-scope LOAD (no RMW serialization)
// with s_sleep(16) backoff; __threadfence() on entry/exit provides
// release/acquire incl. the physical L1/L2 cache ops needed across XCDs.
// gen increases monotonically; target = barrier ordinal (no sense reversal,
// no missed wakeups). Requires *cnt == *gen == 0 at kernel start.
// ===========================================================================
__device__ __forceinline__ void grid_barrier(unsigned* cnt, unsigned* gen,
                                             unsigned target, unsigned nblocks) {
    __syncthreads();                      // all waves' stores issued (vmcnt drained)
    if (threadIdx.x == 0) {
        __threadfence();                  // release: write back this XCD's stores
        unsigned arrived = __hip_atomic_fetch_add(cnt, 1u, __ATOMIC_ACQ_REL,
                                                  __HIP_MEMORY_SCOPE_AGENT);
        if (arrived == nblocks - 1u) {
            __hip_atomic_store(cnt, 0u, __ATOMIC_RELAXED, __HIP_MEMORY_SCOPE_AGENT);
            __hip_atomic_fetch_add(gen, 1u, __ATOMIC_RELEASE, __HIP_MEMORY_SCOPE_AGENT);
        } else {
            while (__hip_atomic_load(gen, __ATOMIC_RELAXED,
                                     __HIP_MEMORY_SCOPE_AGENT) < target) {
                __builtin_amdgcn_s_sleep(16);   // ~1024 cyc between polls
            }
        }
        __threadfence();                  // acquire: invalidate stale L1/L2 lines
    }
    __syncthreads();
}

__device__ __forceinline__ void softmax_row(const float* __restrict__ fp,
                                            const int* __restrict__ adj,
                                            float* __restrict__ wout,
                                            size_t base, int N) {
    const float4* f4 = (const float4*)(fp + base);
    const int4*   a4 = (const int4*)(adj + base);
    float v[DEG];
#pragma unroll
    for (int k = 0; k < DEG / 4; ++k) {
        float4 f = f4[k];
        int4   a = a4[k];
        v[4*k+0] = (a.x == N) ? f.x - 1e7f : f.x;
        v[4*k+1] = (a.y == N) ? f.y - 1e7f : f.y;
        v[4*k+2] = (a.z == N) ? f.z - 1e7f : f.z;
        v[4*k+3] = (a.w == N) ? f.w - 1e7f : f.w;
    }
    float m = v[0];
#pragma unroll
    for (int j = 1; j < DEG; ++j) m = fmaxf(m, v[j]);
    float s = 0.f;
#pragma unroll
    for (int j = 0; j < DEG; ++j) { v[j] = __expf(v[j] - m); s += v[j]; }
    float inv = 1.f / s;
    float4* w4 = (float4*)(wout + base);
#pragma unroll
    for (int k = 0; k < DEG / 4; ++k) {
        float4 o;
        o.x = v[4*k+0] * inv;
        o.y = v[4*k+1] * inv;
        o.z = v[4*k+2] * inv;
        o.w = v[4*k+3] * inv;
        w4[k] = o;
    }
}

// ===========================================================================
// FUSED PATH: 196 blocks x 1024 threads, 2 nodes/thread, edges in registers.
//   phase 0: softmax (own 2 rows)                    | barrier
//   phase 1: gather 2x16 (src,w) pairs into regs; build wave-uniform
//            skip mask for all-zero-weight slots (the padded slots)
//   phase 2: R_1 = relu(-demand)  (R_0==0)           | barrier
//   phase 3: 31 gather-rounds; last one not published (epilogue only
//            needs own r)                            | barrier x30
//   phase 4: flow = own weights row * r
// ===========================================================================
__global__ __launch_bounds__(BLK_F, 4)
void fused2_k(const float* __restrict__ fp, const int* __restrict__ adj,
              const int* __restrict__ in_idx, const float* __restrict__ dem,
              const int* __restrict__ nn, float* __restrict__ wout,
              float* __restrict__ Ra, float* __restrict__ Rb,
              unsigned* __restrict__ bar_cnt, unsigned* __restrict__ bar_gen,
              int nodes) {
    const int tid = blockIdx.x * blockDim.x + threadIdx.x;
    const int T = gridDim.x * blockDim.x;
    const int N = *nn;
    const unsigned nb = gridDim.x;
    unsigned bar = 0;

    const int  n0 = tid, n1 = tid + T;
    const bool a0 = (n0 < nodes), a1 = (n1 < nodes);
    const size_t b0 = (size_t)n0 * DEG, b1 = (size_t)n1 * DEG;

    // ---- phase 0 ----
    if (a0) softmax_row(fp, adj, wout, b0, N);
    if (a1) softmax_row(fp, adj, wout, b1, N);
    grid_barrier(bar_cnt, bar_gen, ++bar, nb);

    // ---- phase 1: register-resident edge tables ----
    int   src0[DEG], src1[DEG];
    float w0[DEG],   w1[DEG];
    float d0 = 0.f, d1 = 0.f;
    unsigned skipA = 0, skipB = 0;
    if (a0) {
        d0 = dem[n0];
        const int* t = in_idx + 3 * b0;
#pragma unroll
        for (int k = 0; k < DEG; ++k) {
            int fi = t[3*k] * N + t[3*k + 1];
            src0[k] = fi;
            w0[k]   = wout[(size_t)fi * DEG + t[3*k + 2]]; // padded -> exactly 0
        }
    } else {
#pragma unroll
        for (int k = 0; k < DEG; ++k) { src0[k] = 0; w0[k] = 0.f; }
    }
    if (a1) {
        d1 = dem[n1];
        const int* t = in_idx + 3 * b1;
#pragma unroll
        for (int k = 0; k < DEG; ++k) {
            int fi = t[3*k] * N + t[3*k + 1];
            src1[k] = fi;
            w1[k]   = wout[(size_t)fi * DEG + t[3*k + 2]];
        }
    } else {
#pragma unroll
        for (int k = 0; k < DEG; ++k) { src1[k] = 0; w1[k] = 0.f; }
    }
    // wave-uniform skip masks (bit k set => every lane's slot-k weight is 0)
#pragma unroll
    for (int k = 0; k < DEG; ++k) {
        if (__ballot(w0[k] != 0.f) == 0ull) skipA |= (1u << k);
        if (__ballot(w1[k] != 0.f) == 0ull) skipB |= (1u << k);
    }
    const unsigned sk0 = __builtin_amdgcn_readfirstlane(skipA);
    const unsigned sk1 = __builtin_amdgcn_readfirstlane(skipB);

    // ---- phase 2: iteration 1 analytically (R_0 == 0) ----
    float r0 = fmaxf(-d0, 0.f), r1 = fmaxf(-d1, 0.f);
    if (a0) Ra[n0] = r0;
    if (a1) Ra[n1] = r1;
    grid_barrier(bar_cnt, bar_gen, ++bar, nb);

    // ---- phase 3: iterations 2..32 ----
    const float* Rin = Ra;
    float*       Rout = Rb;
    for (int t = 1; t < MAX_ITERS; ++t) {
        float acc0 = 0.f, acc1 = 0.f;
#pragma unroll
        for (int k = 0; k < DEG; ++k) {
            if (!((sk0 >> k) & 1u) && a0) acc0 += w0[k] * Rin[src0[k]];
            if (!((sk1 >> k) & 1u) && a1) acc1 += w1[k] * Rin[src1[k]];
        }
        r0 = fmaxf(acc0 - d0, 0.f);
        r1 = fmaxf(acc1 - d1, 0.f);
        if (t < MAX_ITERS - 1) {               // last round publishes nothing
            if (a0) Rout[n0] = r0;
            if (a1) Rout[n1] = r1;
            grid_barrier(bar_cnt, bar_gen, ++bar, nb);
            float* tmp = (float*)Rin; Rin = Rout; Rout = tmp;
        }
    }

    // ---- phase 4: epilogue ----
    if (a0) {
        float4* w4 = (float4*)(wout + b0);
#pragma unroll
        for (int k = 0; k < DEG / 4; ++k) {
            float4 v = w4[k];
            v.x *= r0; v.y *= r0; v.z *= r0; v.w *= r0;
            w4[k] = v;
        }
    }
    if (a1) {
        float4* w4 = (float4*)(wout + b1);
#pragma unroll
        for (int k = 0; k < DEG / 4; ++k) {
            float4 v = w4[k];
            v.x *= r1; v.y *= r1; v.z *= r1; v.w *= r1;
            w4[k] = v;
        }
    }
}

// ===========================================================================
// FALLBACK PATH (round-1 kernels, known-correct 1028 us)
// ===========================================================================
__global__ void softmax_k(const float* __restrict__ fp, const int* __restrict__ adj,
                          const int* __restrict__ nn, float* __restrict__ wout,
                          int nodes) {
    int i = blockIdx.x * blockDim.x + threadIdx.x;
    if (i >= nodes) return;
    softmax_row(fp, adj, wout, (size_t)i * DEG, *nn);
}

__global__ void gather_k(const int* __restrict__ in_idx, const float* __restrict__ w,
                         const int* __restrict__ nn, int* __restrict__ e_src,
                         float* __restrict__ e_w, int edges) {
    int e = blockIdx.x * blockDim.x + threadIdx.x;
    if (e >= edges) return;
    const int N = *nn;
    size_t e3 = 3 * (size_t)e;
    int fi = in_idx[e3] * N + in_idx[e3 + 1];
    e_src[e] = fi;
    e_w[e]   = w[(size_t)fi * DEG + in_idx[e3 + 2]];
}

__global__ void iter_k(const int* __restrict__ e_src, const float* __restrict__ e_w,
                       const float* __restrict__ dem, const float* __restrict__ Rin,
                       float* __restrict__ Rout, int nodes) {
    int i = blockIdx.x * blockDim.x + threadIdx.x;
    if (i >= nodes) return;
    const size_t base = (size_t)i * DEG;
    const int4*   s4 = (const int4*)(e_src + base);
    const float4* w4 = (const float4*)(e_w + base);
    float acc = 0.f;
#pragma unroll
    for (int k = 0; k < DEG / 4; ++k) {
        int4   s = s4[k];
        float4 w = w4[k];
        acc += w.x * Rin[s.x];
        acc += w.y * Rin[s.y];
        acc += w.z * Rin[s.z];
        acc += w.w * Rin[s.w];
    }
    float r = acc - dem[i];
    Rout[i] = r > 0.f ? r : 0.f;
}

__global__ void final_k(const float* __restrict__ w, const float* __restrict__ R,
                        float* __restrict__ out, int nodes) {
    int i = blockIdx.x * blockDim.x + threadIdx.x;
    if (i >= nodes) return;
    float r = R[i];
    const size_t base = (size_t)i * DEG;
    const float4* w4 = (const float4*)(w + base);
    float4* o4 = (float4*)(out + base);
#pragma unroll
    for (int k = 0; k < DEG / 4; ++k) {
        float4 v = w4[k];
        v.x *= r; v.y *= r; v.z *= r; v.w *= r;
        o4[k] = v;
    }
}

extern "C" void kernel_launch(void* const* d_in, const int* in_sizes, int n_in,
                              void* d_out, int out_size, void* d_ws, size_t ws_size,
                              hipStream_t stream) {
    const float* fp  = (const float*)d_in[0];
    const float* dem = (const float*)d_in[1];
    const int*   adj = (const int*)d_in[2];
    const int*   idx = (const int*)d_in[3];
    const int*   nn  = (const int*)d_in[4];

    const int edges = in_sizes[0];   // B*N*D
    const int nodes = in_sizes[1];   // B*N

    float* weights = (float*)d_out;

    char* ws = (char*)d_ws;
    // barrier words live at the head of ws (overlaps e_src, which only the
    // fallback path uses — the two paths are mutually exclusive)
    unsigned* bar_cnt = (unsigned*)ws;
    unsigned* bar_gen = (unsigned*)(ws + 128);
    int*   e_src = (int*)ws;
    float* e_w   = (float*)(ws + (size_t)edges * sizeof(int));
    float* R0    = (float*)(ws + (size_t)edges * sizeof(int) + (size_t)edges * sizeof(float));
    float* R1    = R0 + nodes;

    const int threads_needed = (nodes + 1) / 2;                 // 2 nodes/thread
    const int gf = (threads_needed + BLK_F - 1) / BLK_F;        // fused grid

    int dev = 0, cus = 0, maxBlk = 0;
    hipGetDevice(&dev);
    hipDeviceGetAttribute(&cus, hipDeviceAttributeMultiprocessorCount, dev);
    hipOccupancyMaxActiveBlocksPerMultiprocessor(&maxBlk, (const void*)fused2_k,
                                                 BLK_F, 0);

    if ((long long)maxBlk * cus >= gf) {
        hipMemsetAsync(ws, 0, 256, stream);   // zero barrier words
        void* args[] = { (void*)&fp, (void*)&adj, (void*)&idx, (void*)&dem,
                         (void*)&nn, (void*)&weights, (void*)&R0, (void*)&R1,
                         (void*)&bar_cnt, (void*)&bar_gen, (void*)&nodes };
        hipLaunchCooperativeKernel((const void*)fused2_k, dim3(gf), dim3(BLK_F),
                                   args, 0, stream);
    } else {
        const int blk = 256;
        const int gn = (nodes + blk - 1) / blk;
        const int ge = (edges + blk - 1) / blk;
        hipMemsetAsync(R0, 0, (size_t)nodes * sizeof(float), stream);
        softmax_k<<<gn, blk, 0, stream>>>(fp, adj, nn, weights, nodes);
        gather_k<<<ge, blk, 0, stream>>>(idx, weights, nn, e_src, e_w, edges);
        float* a = R0;
        float* b = R1;
        for (int t = 0; t < MAX_ITERS; ++t) {
            iter_k<<<gn, blk, 0, stream>>>(e_src, e_w, dem, a, b, nodes);
            float* tmp = a; a = b; b = tmp;
        }
        final_k<<<gn, blk, 0, stream>>>(weights, a, (float*)d_out, nodes);
    }
}